// Round 2
// baseline (202.739 us; speedup 1.0000x reference)
//
#include <hip/hip_runtime.h>

// VectorQuantizer: x [2,8,48,48,48] f32, embed [512,8] f32
// d_out: loss (1) | out (1769472) | encodings (221184*512 = 113246208)

#pragma clang fp contract(off)

#define KCB   512
#define SPB   110592            // 48^3
#define NPTS  221184
#define NBLK  864               // NPTS/256
#define OUT_OFF 1
#define ENC_OFF 1769473LL       // 1 + 2*8*SPB
#define ENC_FLOATS 113246208LL
// enc region: 3 unaligned head floats, then 28311551 float4, then 1 tail float
#define FILL4_BASE 442369LL     // (ENC_OFF + 3) / 4
#define FILL4_COUNT 28311551LL
#define TAIL_IDX 115015680LL    // ENC_OFF + ENC_FLOATS - 1

__global__ __launch_bounds__(256) void se_kernel(const float* __restrict__ e,
                                                 float* __restrict__ se) {
    int k = blockIdx.x * 256 + threadIdx.x;
    if (k < KCB) {
        const float4* e4 = (const float4*)(e + (k << 3));
        float4 a = e4[0], b = e4[1];
        // numpy pairwise tree over 8 squared elems (contract off: squares round first)
        float s = ((a.x*a.x + a.y*a.y) + (a.z*a.z + a.w*a.w))
                + ((b.x*b.x + b.y*b.y) + (b.z*b.z + b.w*b.w));
        se[k] = s;
    }
}

// Pure streaming zero-fill of the encodings region (same structure as
// rocclr fillBufferAligned, which sustains ~6.76 TB/s on this chip).
__global__ __launch_bounds__(256) void fill_kernel(float* __restrict__ dout) {
    const long long g0 = (long long)blockIdx.x * 256 + threadIdx.x;
    const long long stride = (long long)gridDim.x * 256;
    float4* o4 = (float4*)dout + FILL4_BASE;
    const float4 z = make_float4(0.f, 0.f, 0.f, 0.f);
    for (long long i = g0; i < FILL4_COUNT; i += stride)
        o4[i] = z;
    if (g0 == 0) {
        dout[ENC_OFF]     = 0.f;
        dout[ENC_OFF + 1] = 0.f;
        dout[ENC_OFF + 2] = 0.f;
        dout[TAIL_IDX]    = 0.f;
    }
}

__global__ __launch_bounds__(256) void argmin_kernel(const float* __restrict__ x,
                                                     const float* __restrict__ e,
                                                     const float* __restrict__ se,
                                                     float* __restrict__ dout,
                                                     float* __restrict__ partials) {
    __shared__ float sred[256];
    const int tid = threadIdx.x;
    const int n   = blockIdx.x * 256 + tid;   // < NPTS (864*256)
    const int b   = n / SPB;
    const int s   = n - b * SPB;

    // this point's 8 channels (coalesced: lanes contiguous in s per channel)
    const float* xb = x + (size_t)b * (8 * SPB) + s;
    float xv[8];
    #pragma unroll
    for (int c = 0; c < 8; ++c) xv[c] = xb[(size_t)c * SPB];

    // sum(x^2), numpy 8-elem pairwise tree
    float sx = ((xv[0]*xv[0] + xv[1]*xv[1]) + (xv[2]*xv[2] + xv[3]*xv[3]))
             + ((xv[4]*xv[4] + xv[5]*xv[5]) + (xv[6]*xv[6] + xv[7]*xv[7]));

    // argmin_k fl( fl(sx+se_k) - 2*dot_k ); strict < keeps first index.
    // k-uniform e/se addresses -> scalar loads (lgkmcnt), pipelined by unroll.
    float best = 3.402823466e38f;
    int   bidx = 0;
    #pragma unroll 4
    for (int k = 0; k < KCB; ++k) {
        const float4* e4 = (const float4*)(e + (k << 3));
        float4 ea = e4[0], eb = e4[1];
        float dot =      xv[0] * ea.x;
        dot = __builtin_fmaf(xv[1], ea.y, dot);
        dot = __builtin_fmaf(xv[2], ea.z, dot);
        dot = __builtin_fmaf(xv[3], ea.w, dot);
        dot = __builtin_fmaf(xv[4], eb.x, dot);
        dot = __builtin_fmaf(xv[5], eb.y, dot);
        dot = __builtin_fmaf(xv[6], eb.z, dot);
        dot = __builtin_fmaf(xv[7], eb.w, dot);
        float ssk = sx + se[k];                      // rounded add, matches ref
        float d   = __builtin_fmaf(-2.0f, dot, ssk); // == fl(ssk - 2*dot)
        if (d < best) { best = d; bidx = k; }
    }

    // quantized values -> out region + loss partial
    const float4* q4 = (const float4*)(e + (bidx << 3));
    float4 qa = q4[0], qb = q4[1];
    float qv[8] = {qa.x, qa.y, qa.z, qa.w, qb.x, qb.y, qb.z, qb.w};
    float part = 0.0f;
    float* outp = dout + OUT_OFF + (size_t)b * (8 * SPB) + s;
    #pragma unroll
    for (int c = 0; c < 8; ++c) {
        float dq = qv[c] - xv[c];
        part += dq * dq;
        outp[(size_t)c * SPB] = qv[c];
    }

    // scatter the one-hot 1.0 (zeros already laid down by fill_kernel,
    // ordering guaranteed by stream order)
    dout[ENC_OFF + (long long)n * KCB + bidx] = 1.0f;

    sred[tid] = part;
    __syncthreads();
    for (int off = 128; off > 0; off >>= 1) {
        if (tid < off) sred[tid] += sred[tid + off];
        __syncthreads();
    }
    if (tid == 0) partials[blockIdx.x] = sred[0];
}

__global__ __launch_bounds__(256) void loss_kernel(const float* __restrict__ partials,
                                                   float* __restrict__ dout) {
    __shared__ float sred[256];
    int t = threadIdx.x;
    float a = 0.0f;
    for (int j = t; j < NBLK; j += 256) a += partials[j];  // fixed order
    sred[t] = a;
    __syncthreads();
    for (int off = 128; off > 0; off >>= 1) {
        if (t < off) sred[t] += sred[t + off];
        __syncthreads();
    }
    if (t == 0) {
        float m = sred[0] / 1769472.0f;
        m = fminf(fmaxf(m, 0.0f), 10.0f);
        dout[0] = m + 0.25f * m;   // q_latent + beta*e_latent (equal values)
    }
}

extern "C" void kernel_launch(void* const* d_in, const int* in_sizes, int n_in,
                              void* d_out, int out_size, void* d_ws, size_t ws_size,
                              hipStream_t stream) {
    const float* x = (const float*)d_in[0];
    const float* e = (const float*)d_in[1];
    float* dout     = (float*)d_out;
    float* se       = (float*)d_ws;     // 512 floats
    float* partials = se + 512;         // 864 floats

    hipLaunchKernelGGL(se_kernel,     dim3(2),    dim3(256), 0, stream, e, se);
    hipLaunchKernelGGL(fill_kernel,   dim3(2048), dim3(256), 0, stream, dout);
    hipLaunchKernelGGL(argmin_kernel, dim3(NBLK), dim3(256), 0, stream, x, e, se, dout, partials);
    hipLaunchKernelGGL(loss_kernel,   dim3(1),    dim3(256), 0, stream, partials, dout);
}

// Round 3
// 174.778 us; speedup vs baseline: 1.1600x; 1.1600x over previous
//
#include <hip/hip_runtime.h>

// VectorQuantizer: x [2,8,48,48,48] f32, embed [512,8] f32
// d_out: loss (1) | out (1769472) | encodings (221184*512 = 113246208)
// Structure: R1 fused (one-hot embedded in the streaming enc write — every
// output byte written exactly once), with a rebuilt argmin k-loop:
// branchless dual even/odd chains, paired-row 64B loads, unroll 4.

#pragma clang fp contract(off)

#define KCB   512
#define SPB   110592          // 48^3
#define NPTS  221184
#define NBLK  864             // NPTS/256
#define OUT_OFF 1
#define ENC_OFF 1769473LL     // 1 + 2*8*SPB ; %4 == 1
#define G4_BASE 442369LL      // (ENC_OFF + 3) / 4

__global__ __launch_bounds__(256) void se_kernel(const float* __restrict__ e,
                                                 float* __restrict__ se) {
    int k = blockIdx.x * 256 + threadIdx.x;
    if (k < KCB) {
        const float4* e4 = (const float4*)(e + (k << 3));
        float4 a = e4[0], b = e4[1];
        // numpy pairwise tree over 8 squared elems (contract off: squares round first)
        float s = ((a.x*a.x + a.y*a.y) + (a.z*a.z + a.w*a.w))
                + ((b.x*b.x + b.y*b.y) + (b.z*b.z + b.w*b.w));
        se[k] = s;
    }
}

__global__ __launch_bounds__(256) void vq_main(const float* __restrict__ x,
                                               const float* __restrict__ e,
                                               const float* __restrict__ se,
                                               float* __restrict__ dout,
                                               float* __restrict__ partials) {
    __shared__ float sred[256];
    __shared__ int   sidx[256];
    const int tid = threadIdx.x;
    const int n   = blockIdx.x * 256 + tid;   // < NPTS (864*256)
    const int b   = n / SPB;
    const int s   = n - b * SPB;

    // this point's 8 channels (coalesced: lanes contiguous in s per channel)
    const float* xb = x + (size_t)b * (8 * SPB) + s;
    float xv[8];
    #pragma unroll
    for (int c = 0; c < 8; ++c) xv[c] = xb[(size_t)c * SPB];

    // sum(x^2), numpy 8-elem pairwise tree
    float sx = ((xv[0]*xv[0] + xv[1]*xv[1]) + (xv[2]*xv[2] + xv[3]*xv[3]))
             + ((xv[4]*xv[4] + xv[5]*xv[5]) + (xv[6]*xv[6] + xv[7]*xv[7]));

    // argmin_k fl( fl(sx+se_k) - 2*dot_k ), first-min tie rule.
    // Dual even/odd chains: branchless cndmask updates, per-k numerics
    // bit-identical to the single-chain version that passed.
    float bestE = 3.402823466e38f, bestO = 3.402823466e38f;
    int   idxE = 0, idxO = 1;
    #pragma unroll 4
    for (int k = 0; k < KCB; k += 2) {
        const float4* ek = (const float4*)(e + (k << 3));  // rows k, k+1 : 64B
        float4 r0a = ek[0], r0b = ek[1], r1a = ek[2], r1b = ek[3];
        float2 s01 = *(const float2*)(se + k);

        float d0 =       xv[0] * r0a.x;
        d0 = __builtin_fmaf(xv[1], r0a.y, d0);
        d0 = __builtin_fmaf(xv[2], r0a.z, d0);
        d0 = __builtin_fmaf(xv[3], r0a.w, d0);
        d0 = __builtin_fmaf(xv[4], r0b.x, d0);
        d0 = __builtin_fmaf(xv[5], r0b.y, d0);
        d0 = __builtin_fmaf(xv[6], r0b.z, d0);
        d0 = __builtin_fmaf(xv[7], r0b.w, d0);
        float dist0 = __builtin_fmaf(-2.0f, d0, sx + s01.x);

        float d1 =       xv[0] * r1a.x;
        d1 = __builtin_fmaf(xv[1], r1a.y, d1);
        d1 = __builtin_fmaf(xv[2], r1a.z, d1);
        d1 = __builtin_fmaf(xv[3], r1a.w, d1);
        d1 = __builtin_fmaf(xv[4], r1b.x, d1);
        d1 = __builtin_fmaf(xv[5], r1b.y, d1);
        d1 = __builtin_fmaf(xv[6], r1b.z, d1);
        d1 = __builtin_fmaf(xv[7], r1b.w, d1);
        float dist1 = __builtin_fmaf(-2.0f, d1, sx + s01.y);

        bool l0 = dist0 < bestE;                 // strict <: first min per chain
        bestE = l0 ? dist0 : bestE;
        idxE  = l0 ? k     : idxE;
        bool l1 = dist1 < bestO;
        bestO = l1 ? dist1 : bestO;
        idxO  = l1 ? k + 1 : idxO;
    }
    // merge: global first-min. bestO wins only if strictly smaller, or equal
    // with a lower index (idxO < idxE possible since chains interleave).
    bool oddWins = (bestO < bestE) || ((bestO == bestE) && (idxO < idxE));
    int bidx = oddWins ? idxO : idxE;

    // quantized values -> out region + loss partial
    const float4* q4 = (const float4*)(e + (bidx << 3));
    float4 qa = q4[0], qb = q4[1];
    float qv[8] = {qa.x, qa.y, qa.z, qa.w, qb.x, qb.y, qb.z, qb.w};
    float part = 0.0f;
    float* outp = dout + OUT_OFF + (size_t)b * (8 * SPB) + s;
    #pragma unroll
    for (int c = 0; c < 8; ++c) {
        float dq = qv[c] - xv[c];
        part += dq * dq;
        outp[(size_t)c * SPB] = qv[c];
    }

    sred[tid] = part;
    sidx[tid] = bidx;
    __syncthreads();
    for (int off = 128; off > 0; off >>= 1) {
        if (tid < off) sred[tid] += sred[tid + off];
        __syncthreads();
    }
    if (tid == 0) partials[blockIdx.x] = sred[0];

    // ---- streaming one-hot encodings write (453 MB, float4, single touch) ----
    float4* o4 = (float4*)dout;
    const long long g4_start = G4_BASE + (long long)blockIdx.x * 32768;
    #pragma unroll 1
    for (int i = 0; i < 128; ++i) {
        int t_lin = i * 256 + tid;
        if (t_lin < 32767) {
            int f  = 3 + (t_lin << 2);   // float index within block's enc region
            int nl = f >> 9;             // local row 0..255
            int k0 = f & 511;
            int id0 = sidx[nl];
            float4 v;
            if (k0 != 511) {
                v.x = (id0 == k0    ) ? 1.0f : 0.0f;
                v.y = (id0 == k0 + 1) ? 1.0f : 0.0f;
                v.z = (id0 == k0 + 2) ? 1.0f : 0.0f;
                v.w = (id0 == k0 + 3) ? 1.0f : 0.0f;
            } else {                      // crosses a row boundary
                int id1 = sidx[nl + 1];
                v.x = (id0 == 511) ? 1.0f : 0.0f;
                v.y = (id1 == 0  ) ? 1.0f : 0.0f;
                v.z = (id1 == 1  ) ? 1.0f : 0.0f;
                v.w = (id1 == 2  ) ? 1.0f : 0.0f;
            }
            o4[g4_start + t_lin] = v;
        }
    }
    const long long gbase = ENC_OFF + (long long)blockIdx.x * 131072;
    if (tid == 0) {
        int id = sidx[0];
        dout[gbase + 0] = (id == 0) ? 1.0f : 0.0f;
        dout[gbase + 1] = (id == 1) ? 1.0f : 0.0f;
        dout[gbase + 2] = (id == 2) ? 1.0f : 0.0f;
    } else if (tid == 1) {
        int id = sidx[255];
        dout[gbase + 131071] = (id == 511) ? 1.0f : 0.0f;
    }
}

__global__ __launch_bounds__(256) void loss_kernel(const float* __restrict__ partials,
                                                   float* __restrict__ dout) {
    __shared__ float sred[256];
    int t = threadIdx.x;
    float a = 0.0f;
    for (int j = t; j < NBLK; j += 256) a += partials[j];  // fixed order
    sred[t] = a;
    __syncthreads();
    for (int off = 128; off > 0; off >>= 1) {
        if (t < off) sred[t] += sred[t + off];
        __syncthreads();
    }
    if (t == 0) {
        float m = sred[0] / 1769472.0f;
        m = fminf(fmaxf(m, 0.0f), 10.0f);
        dout[0] = m + 0.25f * m;   // q_latent + beta*e_latent (equal values)
    }
}

extern "C" void kernel_launch(void* const* d_in, const int* in_sizes, int n_in,
                              void* d_out, int out_size, void* d_ws, size_t ws_size,
                              hipStream_t stream) {
    const float* x = (const float*)d_in[0];
    const float* e = (const float*)d_in[1];
    float* dout     = (float*)d_out;
    float* se       = (float*)d_ws;     // 512 floats
    float* partials = se + 512;         // 864 floats

    hipLaunchKernelGGL(se_kernel,   dim3(2),    dim3(256), 0, stream, e, se);
    hipLaunchKernelGGL(vq_main,     dim3(NBLK), dim3(256), 0, stream, x, e, se, dout, partials);
    hipLaunchKernelGGL(loss_kernel, dim3(1),    dim3(256), 0, stream, partials, dout);
}

// Round 4
// 144.926 us; speedup vs baseline: 1.3989x; 1.2060x over previous
//
#include <hip/hip_runtime.h>

// VectorQuantizer: x [2,8,48,48,48] f32, embed [512,8] f32
// d_out: loss (1) | out (1769472) | encodings (221184*512 = 113246208)
// R4: codebook + se staged in LDS, k-loop reads via wave-uniform ds_read
// (broadcast, conflict-free) -> no global/SMEM latency in the hot loop.

#pragma clang fp contract(off)

#define KCB   512
#define SPB   110592          // 48^3
#define NPTS  221184
#define NBLK  864             // NPTS/256
#define OUT_OFF 1
#define ENC_OFF 1769473LL     // 1 + 2*8*SPB ; %4 == 1
#define G4_BASE 442369LL      // (ENC_OFF + 3) / 4

__global__ __launch_bounds__(256) void vq_main(const float* __restrict__ x,
                                               const float* __restrict__ e,
                                               float* __restrict__ dout,
                                               float* __restrict__ partials) {
    __shared__ float cb[KCB * 8];    // 16 KB codebook, row-major [512][8]
    __shared__ float sse[KCB];       // 2 KB row norms
    __shared__ float sred[256];
    __shared__ int   sidx[256];
    const int tid = threadIdx.x;
    const int n   = blockIdx.x * 256 + tid;   // < NPTS (864*256)
    const int b   = n / SPB;
    const int s   = n - b * SPB;

    // issue this point's 8 channel loads early (coalesced per channel)
    const float* xb = x + (size_t)b * (8 * SPB) + s;
    float xv[8];
    #pragma unroll
    for (int c = 0; c < 8; ++c) xv[c] = xb[(size_t)c * SPB];

    // stage codebook into LDS (1024 float4, coalesced)
    {
        float4* cb4 = (float4*)cb;
        const float4* e4 = (const float4*)e;
        #pragma unroll
        for (int i = 0; i < 4; ++i) cb4[i * 256 + tid] = e4[i * 256 + tid];
    }
    __syncthreads();
    // se from LDS cb, numpy 8-elem pairwise tree (squares round first)
    {
        #pragma unroll
        for (int r = tid; r < KCB; r += 256) {
            const float* row = cb + (r << 3);
            sse[r] = ((row[0]*row[0] + row[1]*row[1]) + (row[2]*row[2] + row[3]*row[3]))
                   + ((row[4]*row[4] + row[5]*row[5]) + (row[6]*row[6] + row[7]*row[7]));
        }
    }
    __syncthreads();

    // sum(x^2), numpy 8-elem pairwise tree
    float sx = ((xv[0]*xv[0] + xv[1]*xv[1]) + (xv[2]*xv[2] + xv[3]*xv[3]))
             + ((xv[4]*xv[4] + xv[5]*xv[5]) + (xv[6]*xv[6] + xv[7]*xv[7]));

    // argmin_k fl( fl(sx+se_k) - 2*dot_k ), first-min tie rule.
    // Dual even/odd branchless chains; all operands from LDS (uniform addr
    // -> ds_read broadcast). Per-k numerics bit-identical to passing version.
    float bestE = 3.402823466e38f, bestO = 3.402823466e38f;
    int   idxE = 0, idxO = 1;
    #pragma unroll 4
    for (int k = 0; k < KCB; k += 2) {
        const float4* ek = (const float4*)(cb + (k << 3));  // rows k, k+1 : 64B
        float4 r0a = ek[0], r0b = ek[1], r1a = ek[2], r1b = ek[3];
        float2 s01 = *(const float2*)(sse + k);

        float d0 =       xv[0] * r0a.x;
        d0 = __builtin_fmaf(xv[1], r0a.y, d0);
        d0 = __builtin_fmaf(xv[2], r0a.z, d0);
        d0 = __builtin_fmaf(xv[3], r0a.w, d0);
        d0 = __builtin_fmaf(xv[4], r0b.x, d0);
        d0 = __builtin_fmaf(xv[5], r0b.y, d0);
        d0 = __builtin_fmaf(xv[6], r0b.z, d0);
        d0 = __builtin_fmaf(xv[7], r0b.w, d0);
        float dist0 = __builtin_fmaf(-2.0f, d0, sx + s01.x);

        float d1 =       xv[0] * r1a.x;
        d1 = __builtin_fmaf(xv[1], r1a.y, d1);
        d1 = __builtin_fmaf(xv[2], r1a.z, d1);
        d1 = __builtin_fmaf(xv[3], r1a.w, d1);
        d1 = __builtin_fmaf(xv[4], r1b.x, d1);
        d1 = __builtin_fmaf(xv[5], r1b.y, d1);
        d1 = __builtin_fmaf(xv[6], r1b.z, d1);
        d1 = __builtin_fmaf(xv[7], r1b.w, d1);
        float dist1 = __builtin_fmaf(-2.0f, d1, sx + s01.y);

        bool l0 = dist0 < bestE;
        bestE = l0 ? dist0 : bestE;
        idxE  = l0 ? k     : idxE;
        bool l1 = dist1 < bestO;
        bestO = l1 ? dist1 : bestO;
        idxO  = l1 ? k + 1 : idxO;
    }
    bool oddWins = (bestO < bestE) || ((bestO == bestE) && (idxO < idxE));
    int bidx = oddWins ? idxO : idxE;

    // quantized values -> out region + loss partial
    const float* qr = cb + (bidx << 3);
    float part = 0.0f;
    float* outp = dout + OUT_OFF + (size_t)b * (8 * SPB) + s;
    #pragma unroll
    for (int c = 0; c < 8; ++c) {
        float q  = qr[c];
        float dq = q - xv[c];
        part += dq * dq;
        outp[(size_t)c * SPB] = q;
    }

    sred[tid] = part;
    sidx[tid] = bidx;
    __syncthreads();
    for (int off = 128; off > 0; off >>= 1) {
        if (tid < off) sred[tid] += sred[tid + off];
        __syncthreads();
    }
    if (tid == 0) partials[blockIdx.x] = sred[0];

    // ---- streaming one-hot encodings write (453 MB, float4, single touch) ----
    float4* o4 = (float4*)dout;
    const long long g4_start = G4_BASE + (long long)blockIdx.x * 32768;
    #pragma unroll 1
    for (int i = 0; i < 128; ++i) {
        int t_lin = i * 256 + tid;
        if (t_lin < 32767) {
            int f  = 3 + (t_lin << 2);   // float index within block's enc region
            int nl = f >> 9;             // local row 0..255
            int k0 = f & 511;
            int id0 = sidx[nl];
            float4 v;
            if (k0 != 511) {
                v.x = (id0 == k0    ) ? 1.0f : 0.0f;
                v.y = (id0 == k0 + 1) ? 1.0f : 0.0f;
                v.z = (id0 == k0 + 2) ? 1.0f : 0.0f;
                v.w = (id0 == k0 + 3) ? 1.0f : 0.0f;
            } else {                      // crosses a row boundary
                int id1 = sidx[nl + 1];
                v.x = (id0 == 511) ? 1.0f : 0.0f;
                v.y = (id1 == 0  ) ? 1.0f : 0.0f;
                v.z = (id1 == 1  ) ? 1.0f : 0.0f;
                v.w = (id1 == 2  ) ? 1.0f : 0.0f;
            }
            o4[g4_start + t_lin] = v;
        }
    }
    const long long gbase = ENC_OFF + (long long)blockIdx.x * 131072;
    if (tid == 0) {
        int id = sidx[0];
        dout[gbase + 0] = (id == 0) ? 1.0f : 0.0f;
        dout[gbase + 1] = (id == 1) ? 1.0f : 0.0f;
        dout[gbase + 2] = (id == 2) ? 1.0f : 0.0f;
    } else if (tid == 1) {
        int id = sidx[255];
        dout[gbase + 131071] = (id == 511) ? 1.0f : 0.0f;
    }
}

__global__ __launch_bounds__(256) void loss_kernel(const float* __restrict__ partials,
                                                   float* __restrict__ dout) {
    __shared__ float sred[256];
    int t = threadIdx.x;
    float a = 0.0f;
    for (int j = t; j < NBLK; j += 256) a += partials[j];  // fixed order
    sred[t] = a;
    __syncthreads();
    for (int off = 128; off > 0; off >>= 1) {
        if (t < off) sred[t] += sred[t + off];
        __syncthreads();
    }
    if (t == 0) {
        float m = sred[0] / 1769472.0f;
        m = fminf(fmaxf(m, 0.0f), 10.0f);
        dout[0] = m + 0.25f * m;   // q_latent + beta*e_latent (equal values)
    }
}

extern "C" void kernel_launch(void* const* d_in, const int* in_sizes, int n_in,
                              void* d_out, int out_size, void* d_ws, size_t ws_size,
                              hipStream_t stream) {
    const float* x = (const float*)d_in[0];
    const float* e = (const float*)d_in[1];
    float* dout     = (float*)d_out;
    float* partials = (float*)d_ws;     // 864 floats

    hipLaunchKernelGGL(vq_main,     dim3(NBLK), dim3(256), 0, stream, x, e, dout, partials);
    hipLaunchKernelGGL(loss_kernel, dim3(1),    dim3(256), 0, stream, partials, dout);
}

// Round 5
// 121.122 us; speedup vs baseline: 1.6738x; 1.1965x over previous
//
#include <hip/hip_runtime.h>

// VectorQuantizer: x [2,8,48,48,48] f32, embed [512,8] f32
// d_out: loss (1) | out (1769472) | encodings (221184*512 = 113246208)
// R5: 64-thread blocks, 4 points/thread (4x LDS amortization of the
// broadcast codebook reads), and the 453 MB zero-stream fused INTO the
// argmin k-loop (fire-and-forget stores drain while VALU computes).
// Ones scattered after s_waitcnt vmcnt(0) (single wave/block -> safe).

#pragma clang fp contract(off)

#define KCB   512
#define SPB   110592          // 48^3
#define NBLK  864             // 221184 / 256 rows per block
#define OUT_OFF 1
#define ENC_OFF 1769473LL     // 1 + 2*8*SPB ; %4 == 1
#define G4_BASE 442369LL      // (ENC_OFF + 3) / 4

__global__ __launch_bounds__(64) void vq_main(const float* __restrict__ x,
                                              const float* __restrict__ e,
                                              float* __restrict__ dout,
                                              float* __restrict__ partials) {
    __shared__ float cb[KCB * 8];    // 16 KB codebook [512][8]
    __shared__ float sse[KCB];       // 2 KB row norms
    const int L   = threadIdx.x;     // 0..63, one wave per block
    const int blk = blockIdx.x;
    const int b   = (blk >= 432) ? 1 : 0;          // blocks don't straddle batch
    const int s0  = blk * 256 - b * SPB;           // spatial base; row q*64+L -> s0+q*64+L

    // x loads early: xv[q][c], coalesced 256B per (c,q)
    const float* xb = x + (size_t)b * (8 * SPB) + s0 + L;
    float xv[4][8];
    #pragma unroll
    for (int q = 0; q < 4; ++q)
        #pragma unroll
        for (int c = 0; c < 8; ++c)
            xv[q][c] = xb[(size_t)c * SPB + q * 64];

    // stage codebook (1024 float4, 16 per lane)
    {
        float4* cb4 = (float4*)cb;
        const float4* e4 = (const float4*)e;
        #pragma unroll
        for (int i = 0; i < 16; ++i) cb4[i * 64 + L] = e4[i * 64 + L];
    }
    __syncthreads();
    // row norms: numpy 8-elem pairwise tree (contract off: squares round first)
    #pragma unroll
    for (int j = 0; j < 8; ++j) {
        int r = j * 64 + L;
        const float* row = cb + (r << 3);
        sse[r] = ((row[0]*row[0] + row[1]*row[1]) + (row[2]*row[2] + row[3]*row[3]))
               + ((row[4]*row[4] + row[5]*row[5]) + (row[6]*row[6] + row[7]*row[7]));
    }
    __syncthreads();

    // sum(x^2), numpy tree, per point
    float sx[4];
    #pragma unroll
    for (int q = 0; q < 4; ++q)
        sx[q] = ((xv[q][0]*xv[q][0] + xv[q][1]*xv[q][1]) + (xv[q][2]*xv[q][2] + xv[q][3]*xv[q][3]))
              + ((xv[q][4]*xv[q][4] + xv[q][5]*xv[q][5]) + (xv[q][6]*xv[q][6] + xv[q][7]*xv[q][7]));

    float bestE[4], bestO[4];
    int   idxE[4], idxO[4];
    #pragma unroll
    for (int q = 0; q < 4; ++q) {
        bestE[q] = 3.402823466e38f; bestO[q] = 3.402823466e38f;
        idxE[q] = 0; idxO[q] = 1;
    }

    // fused zero-stream setup: block's enc region = [ENC_OFF + blk*131072, +131072)
    // alignment %4==1: 3 head floats, 32767 float4 slots, 1 tail float.
    float4* encb = (float4*)dout + (G4_BASE + (long long)blk * 32768);
    float*  encf = dout + (ENC_OFF + (long long)blk * 131072);
    const float4 z4 = make_float4(0.f, 0.f, 0.f, 0.f);

    // main loop: 256 k-pairs; each iter also issues 2 zero float4 stores
    // (slot j = 2i and 2i+1; lane L owns column L of each 64-wide slot row).
    #pragma unroll 1
    for (int i = 0; i < 256; ++i) {
        const int k = i * 2;
        const float4* ek = (const float4*)(cb + (k << 3));  // rows k,k+1 (64B, broadcast)
        float4 r0a = ek[0], r0b = ek[1], r1a = ek[2], r1b = ek[3];
        float2 s01 = *(const float2*)(sse + k);

        encb[(size_t)(2 * i) * 64 + L] = z4;
        if (i < 255 || L < 63)                       // skip slot (511,63): next block's head
            encb[(size_t)(2 * i + 1) * 64 + L] = z4;

        #pragma unroll
        for (int q = 0; q < 4; ++q) {
            float d0 =       xv[q][0] * r0a.x;
            d0 = __builtin_fmaf(xv[q][1], r0a.y, d0);
            d0 = __builtin_fmaf(xv[q][2], r0a.z, d0);
            d0 = __builtin_fmaf(xv[q][3], r0a.w, d0);
            d0 = __builtin_fmaf(xv[q][4], r0b.x, d0);
            d0 = __builtin_fmaf(xv[q][5], r0b.y, d0);
            d0 = __builtin_fmaf(xv[q][6], r0b.z, d0);
            d0 = __builtin_fmaf(xv[q][7], r0b.w, d0);
            float dist0 = __builtin_fmaf(-2.0f, d0, sx[q] + s01.x);

            float d1 =       xv[q][0] * r1a.x;
            d1 = __builtin_fmaf(xv[q][1], r1a.y, d1);
            d1 = __builtin_fmaf(xv[q][2], r1a.z, d1);
            d1 = __builtin_fmaf(xv[q][3], r1a.w, d1);
            d1 = __builtin_fmaf(xv[q][4], r1b.x, d1);
            d1 = __builtin_fmaf(xv[q][5], r1b.y, d1);
            d1 = __builtin_fmaf(xv[q][6], r1b.z, d1);
            d1 = __builtin_fmaf(xv[q][7], r1b.w, d1);
            float dist1 = __builtin_fmaf(-2.0f, d1, sx[q] + s01.y);

            bool l0 = dist0 < bestE[q];
            bestE[q] = l0 ? dist0 : bestE[q];
            idxE[q]  = l0 ? k     : idxE[q];
            bool l1 = dist1 < bestO[q];
            bestO[q] = l1 ? dist1 : bestO[q];
            idxO[q]  = l1 ? k + 1 : idxO[q];
        }
    }

    // head / tail zeros of this block's region
    if (L < 3)   encf[L]      = 0.f;
    if (L == 63) encf[131071] = 0.f;

    // merge chains (global first-min tie rule)
    int bidx[4];
    #pragma unroll
    for (int q = 0; q < 4; ++q) {
        bool ow = (bestO[q] < bestE[q]) || ((bestO[q] == bestE[q]) && (idxO[q] < idxE[q]));
        bidx[q] = ow ? idxO[q] : idxE[q];
    }

    // all zero-stores of THIS wave complete, then scatter the ones
    asm volatile("s_waitcnt vmcnt(0)" ::: "memory");
    #pragma unroll
    for (int q = 0; q < 4; ++q)
        encf[(size_t)(q * 64 + L) * 512 + bidx[q]] = 1.0f;

    // out region + loss partial
    float part = 0.0f;
    float* outp = dout + OUT_OFF + (size_t)b * (8 * SPB) + s0 + L;
    #pragma unroll
    for (int q = 0; q < 4; ++q) {
        const float4* qr4 = (const float4*)(cb + (bidx[q] << 3));
        float4 qa = qr4[0], qb = qr4[1];
        float qv[8] = {qa.x, qa.y, qa.z, qa.w, qb.x, qb.y, qb.z, qb.w};
        #pragma unroll
        for (int c = 0; c < 8; ++c) {
            float dq = qv[c] - xv[q][c];
            part += dq * dq;
            outp[(size_t)c * SPB + q * 64] = qv[c];
        }
    }

    // deterministic wave tree reduction
    #pragma unroll
    for (int off = 32; off > 0; off >>= 1)
        part += __shfl_down(part, off, 64);
    if (L == 0) partials[blk] = part;
}

__global__ __launch_bounds__(256) void loss_kernel(const float* __restrict__ partials,
                                                   float* __restrict__ dout) {
    __shared__ float sred[256];
    int t = threadIdx.x;
    float a = 0.0f;
    for (int j = t; j < NBLK; j += 256) a += partials[j];  // fixed order
    sred[t] = a;
    __syncthreads();
    for (int off = 128; off > 0; off >>= 1) {
        if (t < off) sred[t] += sred[t + off];
        __syncthreads();
    }
    if (t == 0) {
        float m = sred[0] / 1769472.0f;
        m = fminf(fmaxf(m, 0.0f), 10.0f);
        dout[0] = m + 0.25f * m;   // q_latent + beta*e_latent (equal values)
    }
}

extern "C" void kernel_launch(void* const* d_in, const int* in_sizes, int n_in,
                              void* d_out, int out_size, void* d_ws, size_t ws_size,
                              hipStream_t stream) {
    const float* x = (const float*)d_in[0];
    const float* e = (const float*)d_in[1];
    float* dout     = (float*)d_out;
    float* partials = (float*)d_ws;     // 864 floats

    hipLaunchKernelGGL(vq_main,     dim3(NBLK), dim3(64),  0, stream, x, e, dout, partials);
    hipLaunchKernelGGL(loss_kernel, dim3(1),    dim3(256), 0, stream, partials, dout);
}